// Round 19
// baseline (155.278 us; speedup 1.0000x reference)
//
#include <hip/hip_runtime.h>
#include <hip/hip_bf16.h>
#include <math.h>

// Problem constants
#define BT   2048      // B*T tokens
#define DD   1024      // model dim
#define HH   2048      // hidden dim
#define EE   8         // experts
#define CAP  512       // expert capacity = floor(BT*0.25)

typedef unsigned short u16;
typedef unsigned int   u32;
typedef short bf16x8 __attribute__((ext_vector_type(8)));   // 8 bf16 (4 VGPRs) MFMA frag
typedef float f32x4  __attribute__((ext_vector_type(4)));   // MFMA accumulator
typedef u16   u16x4  __attribute__((ext_vector_type(4)));
typedef u32   u32x4  __attribute__((ext_vector_type(4)));

#define AS1 __attribute__((address_space(1)))
#define AS3 __attribute__((address_space(3)))

__device__ __forceinline__ u16 f2bf(float f) {   // RNE fp32->bf16
    union { float f; u32 u; } v; v.f = f;
    return (u16)((v.u + 0x7fffu + ((v.u >> 16) & 1u)) >> 16);
}
__device__ __forceinline__ float bf2f(u16 b) {   // exact bf16->fp32
    union { u32 u; float f; } v; v.u = ((u32)b) << 16;
    return v.f;
}
// pack two fp32 -> two bf16 in one u32 (RNE), gfx950 HW instr (no builtin)
__device__ __forceinline__ u32 pkbf(float lo, float hi) {
    u32 r;
    asm("v_cvt_pk_bf16_f32 %0, %1, %2" : "=v"(r) : "v"(lo), "v"(hi));
    return r;
}

// ---------------------------------------------------------------------------
// 0. pack_w12: w1p[e][kp][n] = pkbf(w[e][2kp][n], w[e][2kp+1][n])
//    bf16 k-pair packing in NATURAL layout (no transpose). Coalesced both
//    sides. Values bit-identical to the old fragment-time pkbf.
// ---------------------------------------------------------------------------
__global__ __launch_bounds__(256) void pack_w12(
    const float* __restrict__ w1, const float* __restrict__ w2,
    u32* __restrict__ w1p, u32* __restrict__ w2p)
{
    const size_t gid = (size_t)blockIdx.x * 256 + threadIdx.x;
    const size_t i4  = gid * 4;                       // u32 index
    const size_t plane = (size_t)(DD / 2) * HH;       // u32 per expert
    const size_t e  = i4 / plane;
    const size_t r  = i4 - e * plane;
    const size_t kp = r / HH;
    const size_t n  = r - kp * HH;
    const float* s1 = w1 + e * (size_t)DD * HH + (2 * kp) * HH + n;
    const float* s2 = w2 + e * (size_t)DD * HH + (2 * kp) * HH + n;
    float4 a0 = *(const float4*)s1;
    float4 a1 = *(const float4*)(s1 + HH);
    float4 b0 = *(const float4*)s2;
    float4 b1 = *(const float4*)(s2 + HH);
    u32x4 o1, o2;
    o1[0] = pkbf(a0.x, a1.x); o1[1] = pkbf(a0.y, a1.y);
    o1[2] = pkbf(a0.z, a1.z); o1[3] = pkbf(a0.w, a1.w);
    o2[0] = pkbf(b0.x, b1.x); o2[1] = pkbf(b0.y, b1.y);
    o2[2] = pkbf(b0.z, b1.z); o2[3] = pkbf(b0.w, b1.w);
    *(u32x4*)(w1p + i4) = o1;
    *(u32x4*)(w2p + i4) = o2;
}

// ---------------------------------------------------------------------------
// 1. Router (fp32, exact): scores = x @ rw + rb ; top-2 ; softmax gates
// ---------------------------------------------------------------------------
__global__ __launch_bounds__(256) void router_kernel(
    const float* __restrict__ x, const float* __restrict__ rw,
    const float* __restrict__ rb, int2* __restrict__ assign,
    float2* __restrict__ gates)
{
    int t   = blockIdx.x;
    int tid = threadIdx.x;
    const float* xr = x + (size_t)t * DD;

    float p[EE];
    #pragma unroll
    for (int e = 0; e < EE; ++e) p[e] = 0.f;

    for (int d = tid; d < DD; d += 256) {
        float xv = xr[d];
        const float4* wr = (const float4*)(rw + (size_t)d * EE);
        float4 w0 = wr[0], w1 = wr[1];
        p[0] += xv * w0.x; p[1] += xv * w0.y; p[2] += xv * w0.z; p[3] += xv * w0.w;
        p[4] += xv * w1.x; p[5] += xv * w1.y; p[6] += xv * w1.z; p[7] += xv * w1.w;
    }
    #pragma unroll
    for (int off = 32; off; off >>= 1) {
        #pragma unroll
        for (int e = 0; e < EE; ++e) p[e] += __shfl_down(p[e], off);
    }
    __shared__ float red[4][EE];
    int wv = tid >> 6, ln = tid & 63;
    if (ln == 0) {
        #pragma unroll
        for (int e = 0; e < EE; ++e) red[wv][e] = p[e];
    }
    __syncthreads();
    if (tid == 0) {
        float s[EE];
        #pragma unroll
        for (int e = 0; e < EE; ++e)
            s[e] = red[0][e] + red[1][e] + red[2][e] + red[3][e] + rb[e];
        int i0 = 0;
        #pragma unroll
        for (int e = 1; e < EE; ++e) if (s[e] > s[i0]) i0 = e;
        int i1 = -1;
        #pragma unroll
        for (int e = 0; e < EE; ++e) {
            if (e == i0) continue;
            if (i1 < 0 || s[e] > s[i1]) i1 = e;
        }
        float e1 = expf(s[i1] - s[i0]);
        float denom = 1.0f + e1;
        assign[t] = make_int2(i0, i1);
        gates[t]  = make_float2(1.0f / denom, e1 / denom);
    }
}

// ---------------------------------------------------------------------------
// 2. Scan (exact reference cumsum semantics — verified round 1)
// ---------------------------------------------------------------------------
__global__ __launch_bounds__(64) void scan_kernel(
    const int2* __restrict__ assign, int4* __restrict__ meta,
    int2* __restrict__ slot_tok)
{
    __shared__ int c0[64][EE];
    __shared__ int cA[64][EE];
    int l = threadIdx.x;

    for (int i = l; i < EE * CAP; i += 64) slot_tok[i] = make_int2(-1, -1);
    #pragma unroll
    for (int e = 0; e < EE; ++e) { c0[l][e] = 0; cA[l][e] = 0; }
    __syncthreads();

    const int CH = BT / 64;
    int t0 = l * CH;

    for (int t = t0; t < t0 + CH; ++t) {
        int2 a = assign[t];
        c0[l][a.x]++; cA[l][a.x]++; cA[l][a.y]++;
    }
    __syncthreads();

    #pragma unroll
    for (int e = 0; e < EE; ++e) {
        int v = c0[l][e], inc = v;
        for (int d = 1; d < 64; d <<= 1) { int u = __shfl_up(inc, d); if (l >= d) inc += u; }
        c0[l][e] = inc - v;
        v = cA[l][e]; inc = v;
        for (int d = 1; d < 64; d <<= 1) { int u = __shfl_up(inc, d); if (l >= d) inc += u; }
        cA[l][e] = inc - v;
    }
    __syncthreads();

    for (int t = t0; t < t0 + CH; ++t) {
        int2 a = assign[t];
        int p0 = ++c0[l][a.x];  cA[l][a.x]++;
        int p1 = ++cA[l][a.y];
        int4 m;
        m.x = a.x; m.y = (p0 < CAP) ? p0 : -1;
        m.z = a.y; m.w = (p1 < CAP) ? p1 : -1;
        meta[t] = m;
        int* st = (int*)slot_tok;
        if (p0 < CAP) st[(a.x * CAP + p0) * 2 + 0] = t;
        if (p1 < CAP) st[(a.y * CAP + p1) * 2 + 1] = t;
    }
}

// ---------------------------------------------------------------------------
// 3. Gather -> bf16 grouped (E, CAP, DD)
// ---------------------------------------------------------------------------
__global__ __launch_bounds__(256) void gather_bf16(
    const float* __restrict__ x, const int2* __restrict__ slot_tok,
    u16* __restrict__ G)
{
    int es = blockIdx.x;
    int d  = threadIdx.x * 4;
    int2 st = slot_tok[es];
    float4 r = make_float4(0.f, 0.f, 0.f, 0.f);
    if (st.x >= 0) r = *(const float4*)(x + (size_t)st.x * DD + d);
    if (st.y >= 0) {
        float4 v = *(const float4*)(x + (size_t)st.y * DD + d);
        r.x += v.x; r.y += v.y; r.z += v.z; r.w += v.w;
    }
    u16x4 o;
    o[0] = f2bf(r.x); o[1] = f2bf(r.y); o[2] = f2bf(r.z); o[3] = f2bf(r.w);
    *(u16x4*)(G + (size_t)es * DD + d) = o;
}

// ---------------------------------------------------------------------------
// LDS layouts: verified r4/r8/r13 algebra.
// gemm1 (this round): r18 structure, B swapped to k-pair-packed bf16 u32
//   tiles [kp<32][64 u32] (256-B rows — SAME row geometry as before):
//   staging: 1 inst/wave/matrix, rows 4w..4w+3, src chunk pre-XOR
//   5*(w>>1)&15 (kp>>3 == w>>1 wave-uniform); read: u32 idx kp*64 +
//   (((n>>2)^(5*(lqh>>1)))&15)*4 + (n&3), kp = lqh*4+i -> 2 lanes/bank
//   (free; XOR-5 disjoint halves), k-pair order identical to old pkbf
//   fragments (bit-identical values).  LDS 48 KB -> 3 blk/CU (was 2).
// gemm2: r18 BK=128 verbatim (fast, verified).
// ---------------------------------------------------------------------------

// ---------------------------------------------------------------------------
// 5. GEMM1 (MFMA): H = gelu((G@w1)*(G@w2)) ; 256x64 tiles, BK=64, 512 thr
// ---------------------------------------------------------------------------
__global__ __launch_bounds__(512, 4) void gemm1_mfma(
    const u16* __restrict__ G, const u32* __restrict__ W1p,
    const u32* __restrict__ W2p, u16* __restrict__ H)
{
    __shared__ u16 As [256 * 64];        // 32 KB (2 halves x 16 chunks x 1KB)
    __shared__ u32 B1s[32 * 64];         //  8 KB (32 kp-rows x 256 B)
    __shared__ u32 B2s[32 * 64];         //  8 KB   (48 KB total)

    const int e  = blockIdx.z;
    const int n0 = blockIdx.x * 64;
    const int m0 = blockIdx.y * 256;
    const int tid  = threadIdx.x;
    const int lane = tid & 63;
    const int w    = tid >> 6;          // 0..7
    const int wr = w >> 2, wc = w & 3;  // 2M x 4N wave grid
    const int lr = lane & 15, lq = lane >> 4;

    const char* Ab  = (const char*)(G + (size_t)e * CAP * DD + (size_t)m0 * DD);
    const char* W1b = (const char*)(W1p + (size_t)e * (DD / 2) * HH + n0);
    const char* W2b = (const char*)(W2p + (size_t)e * (DD / 2) * HH + n0);

    // A staging coords (verified round 4 algebra)
    const int srow = lane >> 2;
    const int skb  = ((lane & 3) ^ ((lane >> 3) & 3)) * 16;
    // B staging coords: wave w covers kp-rows 4w..4w+3; kp>>3 == w>>1
    const int bkrow = lane >> 4;                               // row within inst
    const int bscc  = ((lane & 15) ^ ((5 * (w >> 1)) & 15)) * 16;

    f32x4 acc1[8] = {};
    f32x4 acc2[8] = {};

    for (int k0 = 0; k0 < DD; k0 += 64) {
        const int k0p = k0 >> 1;
        // ---- A staging (DMA): 32 insts, wave w does idx 4w..4w+3 ----
        #pragma unroll
        for (int j = 0; j < 4; ++j) {
            const int idx = 4 * w + j;
            const int h = idx >> 4, c = idx & 15;
            const size_t rb = (size_t)(c * 16 + srow) * (DD * 2)
                            + (size_t)k0 * 2 + h * 64 + skb;
            __builtin_amdgcn_global_load_lds((const AS1 void*)(Ab + rb),
                (AS3 void*)((char*)As + idx * 1024), 16, 0, 0);
        }
        // ---- B staging (DMA): 1 inst per wave per matrix ----
        {
            const size_t sb = (size_t)(k0p + 4 * w + bkrow) * (HH * 4) + bscc;
            __builtin_amdgcn_global_load_lds((const AS1 void*)(W1b + sb),
                (AS3 void*)((char*)B1s + w * 1024), 16, 0, 0);
            __builtin_amdgcn_global_load_lds((const AS1 void*)(W2b + sb),
                (AS3 void*)((char*)B2s + w * 1024), 16, 0, 0);
        }
        __syncthreads();
        // ---- compute: two k-halves of 32 ----
        #pragma unroll
        for (int h = 0; h < 2; ++h) {
            bf16x8 av[8];
            #pragma unroll
            for (int m = 0; m < 8; ++m) {
                const int row = wr * 128 + m * 16 + lr;
                const int sl  = (lq ^ ((row >> 1) & 3)) * 16;
                av[m] = *(const bf16x8*)((const char*)As + h * 16384 + row * 64 + sl);
            }
            const int n   = wc * 16 + lr;
            const int lqh = h * 4 + lq;                  // 0..7
            const int col = ((((n >> 2) ^ (5 * (lqh >> 1))) & 15) << 2) + (n & 3);
            union { u32 q[4]; bf16x8 v; } u1, u2;
            #pragma unroll
            for (int j = 0; j < 2; ++j) {
                int o = (lqh * 4 + 2 * j) * 256 + col * 4;   // kp-pair bytes
                asm("" : "+v"(o));                            // pin for ds_read2
                u1.q[2*j]   = *(const u32*)((const char*)B1s + o);
                u1.q[2*j+1] = *(const u32*)((const char*)B1s + o + 256);
                u2.q[2*j]   = *(const u32*)((const char*)B2s + o);
                u2.q[2*j+1] = *(const u32*)((const char*)B2s + o + 256);
            }
            const bf16x8 b1 = u1.v, b2 = u2.v;
            #pragma unroll
            for (int m = 0; m < 8; ++m) {
                acc1[m] = __builtin_amdgcn_mfma_f32_16x16x32_bf16(av[m], b1, acc1[m], 0, 0, 0);
                acc2[m] = __builtin_amdgcn_mfma_f32_16x16x32_bf16(av[m], b2, acc2[m], 0, 0, 0);
            }
        }
        __syncthreads();
    }

    u16* He = H + (size_t)e * CAP * HH;
    const float gc0 = 0.7978845608028654f, gc1 = 0.044715f;
    const int cc = n0 + wc * 16 + lr;
    #pragma unroll
    for (int m = 0; m < 8; ++m)
        #pragma unroll
        for (int r = 0; r < 4; ++r) {
            const int rr = m0 + wr * 128 + m * 16 + lq * 4 + r;
            float hv = acc1[m][r] * acc2[m][r];
            float u  = gc0 * (hv + gc1 * hv * hv * hv);
            float th = 1.f - 2.f / (__expf(2.f * u) + 1.f);   // tanh(u)
            He[(size_t)rr * HH + cc] = f2bf(0.5f * hv * (1.f + th));
        }
}

// ---------------------------------------------------------------------------
// 6. GEMM2 (MFMA): EO = H @ w3 ; 128x64 tiles, BK=128, 256 thr (r18 verbatim)
// ---------------------------------------------------------------------------
__global__ __launch_bounds__(256, 2) void gemm2_mfma(
    const u16* __restrict__ Hin, const float* __restrict__ W3, u16* __restrict__ EO)
{
    __shared__ u16   As[128 * 128];      // 32 KB (4 halves x 8 chunks x 1KB)
    __shared__ float Bs[128 * 64];       // 32 KB   (64 KB total)

    const int bid  = blockIdx.x;
    const int e    = bid & 7;
    const int rest = bid >> 3;           // 0..63
    const int m0   = (rest & 3) * 128;
    const int n0   = (rest >> 2) * 64;

    const int tid  = threadIdx.x;
    const int lane = tid & 63;
    const int w    = tid >> 6;          // 0..3 (1M x 4N wave grid)
    const int lr = lane & 15, lq = lane >> 4;

    const char* Ab  = (const char*)(Hin + (size_t)e * CAP * HH + (size_t)m0 * HH);
    const char* W3b = (const char*)(W3 + (size_t)e * HH * DD + n0);

    const int srow = lane >> 2;
    const int skb  = ((lane & 3) ^ ((lane >> 3) & 3)) * 16;
    const int brow_i = lane >> 4;

    f32x4 acc[8] = {};

    for (int k0 = 0; k0 < HH; k0 += 128) {
        #pragma unroll
        for (int j = 0; j < 8; ++j) {
            const int idx = 8 * w + j;
            const int h = idx >> 3, c = idx & 7;
            const size_t rb = (size_t)(c * 16 + srow) * (HH * 2)
                            + (size_t)k0 * 2 + h * 64 + skb;
            __builtin_amdgcn_global_load_lds((const AS1 void*)(Ab + rb),
                (AS3 void*)((char*)As + idx * 1024), 16, 0, 0);
        }
        #pragma unroll
        for (int i = 0; i < 8; ++i) {
            const int krow = w * 32 + i * 4 + brow_i;
            const int bscc = ((lane & 15) ^ ((5 * (4 * w + (i >> 1))) & 15)) * 16;
            const size_t sb = (size_t)(k0 + krow) * (DD * 4) + bscc;
            __builtin_amdgcn_global_load_lds((const AS1 void*)(W3b + sb),
                (AS3 void*)((char*)Bs + w * 8192 + i * 1024), 16, 0, 0);
        }
        __syncthreads();
        #pragma unroll
        for (int h = 0; h < 4; ++h) {
            bf16x8 av[8];
            #pragma unroll
            for (int m = 0; m < 8; ++m) {
                const int row = m * 16 + lr;
                const int sl  = (lq ^ ((row >> 1) & 3)) * 16;
                av[m] = *(const bf16x8*)((const char*)As + h * 8192 + row * 64 + sl);
            }
            const int n   = w * 16 + lr;
            const int lqh = h * 4 + lq;               // 0..15
            const int cb  = ((((n >> 2) ^ (5 * lqh)) & 15) << 4) + (n & 3) * 4;
            union { u32 q[4]; bf16x8 v; } u3;
            #pragma unroll
            for (int i = 0; i < 4; ++i) {
                int o = (lqh * 8 + 2 * i) * 256 + cb;
                asm("" : "+v"(o));
                u3.q[i] = pkbf(*(const float*)((const char*)Bs + o),
                               *(const float*)((const char*)Bs + o + 256));
            }
            const bf16x8 b3 = u3.v;
            #pragma unroll
            for (int m = 0; m < 8; ++m)
                acc[m] = __builtin_amdgcn_mfma_f32_16x16x32_bf16(av[m], b3, acc[m], 0, 0, 0);
        }
        __syncthreads();
    }

    u16* Oe = EO + (size_t)e * CAP * DD;
    const int cc = n0 + w * 16 + lr;
    #pragma unroll
    for (int m = 0; m < 8; ++m)
        #pragma unroll
        for (int r = 0; r < 4; ++r) {
            const int rr = m0 + m * 16 + lq * 4 + r;
            Oe[(size_t)rr * DD + cc] = f2bf(acc[m][r]);
        }
}

// ---------------------------------------------------------------------------
// 7. Combine: out[t] = g0*(kept0 ? EO[e0][p0] : x) + g1*(...)   (EO is bf16)
// ---------------------------------------------------------------------------
__global__ __launch_bounds__(256) void combine_kernel(
    const float* __restrict__ x, const u16* __restrict__ EO,
    const int4* __restrict__ meta, const float2* __restrict__ gates,
    float* __restrict__ out)
{
    int t = blockIdx.x;
    int d = threadIdx.x * 4;
    int4  m = meta[t];
    float2 g = gates[t];
    float4 xv = *(const float4*)(x + (size_t)t * DD + d);
    float4 v0 = xv, v1 = xv;
    if (m.y >= 0) {
        u16x4 q = *(const u16x4*)(EO + ((size_t)m.x * CAP + m.y) * DD + d);
        v0 = make_float4(bf2f(q[0]), bf2f(q[1]), bf2f(q[2]), bf2f(q[3]));
    }
    if (m.w >= 0) {
        u16x4 q = *(const u16x4*)(EO + ((size_t)m.z * CAP + m.w) * DD + d);
        v1 = make_float4(bf2f(q[0]), bf2f(q[1]), bf2f(q[2]), bf2f(q[3]));
    }
    float4 r;
    r.x = g.x * v0.x + g.y * v1.x;
    r.y = g.x * v0.y + g.y * v1.y;
    r.z = g.x * v0.z + g.y * v1.z;
    r.w = g.x * v0.w + g.y * v1.w;
    *(float4*)(out + (size_t)t * DD + d) = r;
}

// ---------------------------------------------------------------------------
extern "C" void kernel_launch(void* const* d_in, const int* in_sizes, int n_in,
                              void* d_out, int out_size, void* d_ws, size_t ws_size,
                              hipStream_t stream)
{
    const float* x  = (const float*)d_in[0];
    const float* rw = (const float*)d_in[1];
    const float* rb = (const float*)d_in[2];
    const float* w1 = (const float*)d_in[3];
    const float* w2 = (const float*)d_in[4];
    const float* w3 = (const float*)d_in[5];
    float* out = (float*)d_out;

    char* ws = (char*)d_ws;
    size_t off = 0;
    auto alloc = [&](size_t bytes) { char* p = ws + off; off = (off + bytes + 255) & ~(size_t)255; return p; };

    int2*   assign   = (int2*)  alloc(BT * sizeof(int2));
    float2* gates    = (float2*)alloc(BT * sizeof(float2));
    int4*   meta     = (int4*)  alloc(BT * sizeof(int4));
    int2*   slot_tok = (int2*)  alloc(EE * CAP * sizeof(int2));
    u16*    grouped  = (u16*)   alloc((size_t)EE * CAP * DD * 2);   //  8.4 MB
    u16*    Hbuf     = (u16*)   alloc((size_t)EE * CAP * HH * 2);   // 16.8 MB
    u16*    eo       = (u16*)   alloc((size_t)EE * CAP * DD * 2);   //  8.4 MB
    u32*    w1p      = (u32*)   alloc((size_t)EE * (DD / 2) * HH * 4);  // 33.6 MB
    u32*    w2p      = (u32*)   alloc((size_t)EE * (DD / 2) * HH * 4);  // 33.6 MB
    (void)ws_size;

    // bf16 k-pair packing of w1/w2 (natural layout; 192 MB traffic)
    pack_w12<<<(EE * (DD / 2) * HH) / 1024, 256, 0, stream>>>(w1, w2, w1p, w2p);

    router_kernel<<<BT, 256, 0, stream>>>(x, rw, rb, assign, gates);
    scan_kernel<<<1, 64, 0, stream>>>(assign, meta, slot_tok);
    gather_bf16<<<EE * CAP, 256, 0, stream>>>(x, slot_tok, grouped);

    gemm1_mfma<<<dim3(HH / 64, CAP / 256, EE), 512, 0, stream>>>(grouped, w1p, w2p, Hbuf);
    gemm2_mfma<<<512, 256, 0, stream>>>(Hbuf, w3, eo);

    combine_kernel<<<BT, 256, 0, stream>>>(x, eo, meta, gates, out);
}

// Round 20
// 116.206 us; speedup vs baseline: 1.3362x; 1.3362x over previous
//
#include <hip/hip_runtime.h>
#include <hip/hip_bf16.h>
#include <math.h>

// Problem constants
#define BT   2048      // B*T tokens
#define DD   1024      // model dim
#define HH   2048      // hidden dim
#define EE   8         // experts
#define CAP  512       // expert capacity = floor(BT*0.25)

typedef unsigned short u16;
typedef unsigned int   u32;
typedef short bf16x8 __attribute__((ext_vector_type(8)));   // 8 bf16 (4 VGPRs) MFMA frag
typedef float f32x4  __attribute__((ext_vector_type(4)));   // MFMA accumulator
typedef u16   u16x4  __attribute__((ext_vector_type(4)));

#define AS1 __attribute__((address_space(1)))
#define AS3 __attribute__((address_space(3)))

__device__ __forceinline__ u16 f2bf(float f) {   // RNE fp32->bf16
    union { float f; u32 u; } v; v.f = f;
    return (u16)((v.u + 0x7fffu + ((v.u >> 16) & 1u)) >> 16);
}
__device__ __forceinline__ float bf2f(u16 b) {   // exact bf16->fp32
    union { u32 u; float f; } v; v.u = ((u32)b) << 16;
    return v.f;
}
// pack two fp32 -> two bf16 in one u32 (RNE), gfx950 HW instr (no builtin)
__device__ __forceinline__ u32 pkbf(float lo, float hi) {
    u32 r;
    asm("v_cvt_pk_bf16_f32 %0, %1, %2" : "=v"(r) : "v"(lo), "v"(hi));
    return r;
}

// ---------------------------------------------------------------------------
// 1. Router (fp32, exact): scores = x @ rw + rb ; top-2 ; softmax gates
// ---------------------------------------------------------------------------
__global__ __launch_bounds__(256) void router_kernel(
    const float* __restrict__ x, const float* __restrict__ rw,
    const float* __restrict__ rb, int2* __restrict__ assign,
    float2* __restrict__ gates)
{
    int t   = blockIdx.x;
    int tid = threadIdx.x;
    const float* xr = x + (size_t)t * DD;

    float p[EE];
    #pragma unroll
    for (int e = 0; e < EE; ++e) p[e] = 0.f;

    for (int d = tid; d < DD; d += 256) {
        float xv = xr[d];
        const float4* wr = (const float4*)(rw + (size_t)d * EE);
        float4 w0 = wr[0], w1 = wr[1];
        p[0] += xv * w0.x; p[1] += xv * w0.y; p[2] += xv * w0.z; p[3] += xv * w0.w;
        p[4] += xv * w1.x; p[5] += xv * w1.y; p[6] += xv * w1.z; p[7] += xv * w1.w;
    }
    #pragma unroll
    for (int off = 32; off; off >>= 1) {
        #pragma unroll
        for (int e = 0; e < EE; ++e) p[e] += __shfl_down(p[e], off);
    }
    __shared__ float red[4][EE];
    int wv = tid >> 6, ln = tid & 63;
    if (ln == 0) {
        #pragma unroll
        for (int e = 0; e < EE; ++e) red[wv][e] = p[e];
    }
    __syncthreads();
    if (tid == 0) {
        float s[EE];
        #pragma unroll
        for (int e = 0; e < EE; ++e)
            s[e] = red[0][e] + red[1][e] + red[2][e] + red[3][e] + rb[e];
        int i0 = 0;
        #pragma unroll
        for (int e = 1; e < EE; ++e) if (s[e] > s[i0]) i0 = e;
        int i1 = -1;
        #pragma unroll
        for (int e = 0; e < EE; ++e) {
            if (e == i0) continue;
            if (i1 < 0 || s[e] > s[i1]) i1 = e;
        }
        float e1 = expf(s[i1] - s[i0]);
        float denom = 1.0f + e1;
        assign[t] = make_int2(i0, i1);
        gates[t]  = make_float2(1.0f / denom, e1 / denom);
    }
}

// ---------------------------------------------------------------------------
// 2. Scan (exact reference cumsum semantics — verified round 1)
// ---------------------------------------------------------------------------
__global__ __launch_bounds__(64) void scan_kernel(
    const int2* __restrict__ assign, int4* __restrict__ meta,
    int2* __restrict__ slot_tok)
{
    __shared__ int c0[64][EE];
    __shared__ int cA[64][EE];
    int l = threadIdx.x;

    for (int i = l; i < EE * CAP; i += 64) slot_tok[i] = make_int2(-1, -1);
    #pragma unroll
    for (int e = 0; e < EE; ++e) { c0[l][e] = 0; cA[l][e] = 0; }
    __syncthreads();

    const int CH = BT / 64;
    int t0 = l * CH;

    for (int t = t0; t < t0 + CH; ++t) {
        int2 a = assign[t];
        c0[l][a.x]++; cA[l][a.x]++; cA[l][a.y]++;
    }
    __syncthreads();

    #pragma unroll
    for (int e = 0; e < EE; ++e) {
        int v = c0[l][e], inc = v;
        for (int d = 1; d < 64; d <<= 1) { int u = __shfl_up(inc, d); if (l >= d) inc += u; }
        c0[l][e] = inc - v;
        v = cA[l][e]; inc = v;
        for (int d = 1; d < 64; d <<= 1) { int u = __shfl_up(inc, d); if (l >= d) inc += u; }
        cA[l][e] = inc - v;
    }
    __syncthreads();

    for (int t = t0; t < t0 + CH; ++t) {
        int2 a = assign[t];
        int p0 = ++c0[l][a.x];  cA[l][a.x]++;
        int p1 = ++cA[l][a.y];
        int4 m;
        m.x = a.x; m.y = (p0 < CAP) ? p0 : -1;
        m.z = a.y; m.w = (p1 < CAP) ? p1 : -1;
        meta[t] = m;
        int* st = (int*)slot_tok;
        if (p0 < CAP) st[(a.x * CAP + p0) * 2 + 0] = t;
        if (p1 < CAP) st[(a.y * CAP + p1) * 2 + 1] = t;
    }
}

// ---------------------------------------------------------------------------
// 3. Gather -> bf16 grouped (E, CAP, DD)
// ---------------------------------------------------------------------------
__global__ __launch_bounds__(256) void gather_bf16(
    const float* __restrict__ x, const int2* __restrict__ slot_tok,
    u16* __restrict__ G)
{
    int es = blockIdx.x;
    int d  = threadIdx.x * 4;
    int2 st = slot_tok[es];
    float4 r = make_float4(0.f, 0.f, 0.f, 0.f);
    if (st.x >= 0) r = *(const float4*)(x + (size_t)st.x * DD + d);
    if (st.y >= 0) {
        float4 v = *(const float4*)(x + (size_t)st.y * DD + d);
        r.x += v.x; r.y += v.y; r.z += v.z; r.w += v.w;
    }
    u16x4 o;
    o[0] = f2bf(r.x); o[1] = f2bf(r.y); o[2] = f2bf(r.z); o[3] = f2bf(r.w);
    *(u16x4*)(G + (size_t)es * DD + d) = o;
}

// ---------------------------------------------------------------------------
// LDS layouts: verified r4/r8/r13 algebra.
// Best-measured configuration (round 18, 116.5 us): gemm1 = r14 structure
// (BM=256/BK=64, 512 thr, 3-D grid, no swizzle); gemm2 = expert-per-XCD
// swizzle + BK=128 (h<4 k-halves, drain events 32 -> 16).
// ---------------------------------------------------------------------------

// ---------------------------------------------------------------------------
// 5. GEMM1 (MFMA): H = gelu((G@w1)*(G@w2)) ; 256x64 tiles, BK=64, 512 thr
// ---------------------------------------------------------------------------
__global__ __launch_bounds__(512, 4) void gemm1_mfma(
    const u16* __restrict__ G, const float* __restrict__ W1,
    const float* __restrict__ W2, u16* __restrict__ H)
{
    __shared__ u16   As [256 * 64];      // 32 KB (2 halves x 16 chunks x 1KB)
    __shared__ float B1s[64 * 64];       // 16 KB
    __shared__ float B2s[64 * 64];       // 16 KB   (64 KB total)

    const int e  = blockIdx.z;
    const int n0 = blockIdx.x * 64;
    const int m0 = blockIdx.y * 256;
    const int tid  = threadIdx.x;
    const int lane = tid & 63;
    const int w    = tid >> 6;          // 0..7
    const int wr = w >> 2, wc = w & 3;  // 2M x 4N wave grid
    const int lr = lane & 15, lq = lane >> 4;

    const char* Ab  = (const char*)(G + (size_t)e * CAP * DD + (size_t)m0 * DD);
    const char* W1b = (const char*)(W1 + (size_t)e * DD * HH + n0);
    const char* W2b = (const char*)(W2 + (size_t)e * DD * HH + n0);

    // A staging coords (verified round 4 algebra)
    const int srow = lane >> 2;
    const int skb  = ((lane & 3) ^ ((lane >> 3) & 3)) * 16;
    // B staging coords: inst covers 4 rows; wave w covers rows w*8..w*8+7
    const int brow_i = lane >> 4;                       // row within inst
    const int bscc   = ((lane & 15) ^ ((5 * w) & 15)) * 16;  // src chunk pre-XOR

    f32x4 acc1[8] = {};
    f32x4 acc2[8] = {};

    for (int k0 = 0; k0 < DD; k0 += 64) {
        // ---- A staging (DMA): 32 insts, wave w does idx 4w..4w+3 ----
        #pragma unroll
        for (int j = 0; j < 4; ++j) {
            const int idx = 4 * w + j;
            const int h = idx >> 4, c = idx & 15;
            const size_t rb = (size_t)(c * 16 + srow) * (DD * 2)
                            + (size_t)k0 * 2 + h * 64 + skb;
            __builtin_amdgcn_global_load_lds((const AS1 void*)(Ab + rb),
                (AS3 void*)((char*)As + idx * 1024), 16, 0, 0);
        }
        // ---- B staging (DMA): 2 insts per matrix per wave ----
        #pragma unroll
        for (int i = 0; i < 2; ++i) {
            const int krow = w * 8 + i * 4 + brow_i;
            const size_t sb = (size_t)(k0 + krow) * (HH * 4) + bscc;
            __builtin_amdgcn_global_load_lds((const AS1 void*)(W1b + sb),
                (AS3 void*)((char*)B1s + w * 2048 + i * 1024), 16, 0, 0);
            __builtin_amdgcn_global_load_lds((const AS1 void*)(W2b + sb),
                (AS3 void*)((char*)B2s + w * 2048 + i * 1024), 16, 0, 0);
        }
        __syncthreads();
        // ---- compute: two k-halves of 32 ----
        #pragma unroll
        for (int h = 0; h < 2; ++h) {
            bf16x8 av[8];
            #pragma unroll
            for (int m = 0; m < 8; ++m) {
                const int row = wr * 128 + m * 16 + lr;
                const int sl  = (lq ^ ((row >> 1) & 3)) * 16;
                av[m] = *(const bf16x8*)((const char*)As + h * 16384 + row * 64 + sl);
            }
            const int n   = wc * 16 + lr;
            const int lqh = h * 4 + lq;
            const int cb  = ((((n >> 2) ^ (5 * lqh)) & 15) << 4) + (n & 3) * 4;
            union { u32 q[4]; bf16x8 v; } u1, u2;
            #pragma unroll
            for (int i = 0; i < 4; ++i) {
                int o = (lqh * 8 + 2 * i) * 256 + cb;    // k-pair (2i, 2i+1)
                asm("" : "+v"(o));                       // pin base for ds_read2
                u1.q[i] = pkbf(*(const float*)((const char*)B1s + o),
                               *(const float*)((const char*)B1s + o + 256));
                u2.q[i] = pkbf(*(const float*)((const char*)B2s + o),
                               *(const float*)((const char*)B2s + o + 256));
            }
            const bf16x8 b1 = u1.v, b2 = u2.v;
            #pragma unroll
            for (int m = 0; m < 8; ++m) {
                acc1[m] = __builtin_amdgcn_mfma_f32_16x16x32_bf16(av[m], b1, acc1[m], 0, 0, 0);
                acc2[m] = __builtin_amdgcn_mfma_f32_16x16x32_bf16(av[m], b2, acc2[m], 0, 0, 0);
            }
        }
        __syncthreads();
    }

    u16* He = H + (size_t)e * CAP * HH;
    const float gc0 = 0.7978845608028654f, gc1 = 0.044715f;
    const int cc = n0 + wc * 16 + lr;
    #pragma unroll
    for (int m = 0; m < 8; ++m)
        #pragma unroll
        for (int r = 0; r < 4; ++r) {
            const int rr = m0 + wr * 128 + m * 16 + lq * 4 + r;
            float hv = acc1[m][r] * acc2[m][r];
            float u  = gc0 * (hv + gc1 * hv * hv * hv);
            float th = 1.f - 2.f / (__expf(2.f * u) + 1.f);   // tanh(u)
            He[(size_t)rr * HH + cc] = f2bf(0.5f * hv * (1.f + th));
        }
}

// ---------------------------------------------------------------------------
// 6. GEMM2 (MFMA): EO = H @ w3 ; 128x64 tiles, BK=128, 256 thr, 2 blk/CU
//    (expert-per-XCD swizzle; h<4 k-halves; drain events 32 -> 16)
// ---------------------------------------------------------------------------
__global__ __launch_bounds__(256, 2) void gemm2_mfma(
    const u16* __restrict__ Hin, const float* __restrict__ W3, u16* __restrict__ EO)
{
    __shared__ u16   As[128 * 128];      // 32 KB (4 halves x 8 chunks x 1KB)
    __shared__ float Bs[128 * 64];       // 32 KB   (64 KB total)

    // expert-per-XCD swizzle
    const int bid  = blockIdx.x;
    const int e    = bid & 7;
    const int rest = bid >> 3;           // 0..63
    const int m0   = (rest & 3) * 128;
    const int n0   = (rest >> 2) * 64;

    const int tid  = threadIdx.x;
    const int lane = tid & 63;
    const int w    = tid >> 6;          // 0..3 (1M x 4N wave grid)
    const int lr = lane & 15, lq = lane >> 4;

    const char* Ab  = (const char*)(Hin + (size_t)e * CAP * HH + (size_t)m0 * HH);
    const char* W3b = (const char*)(W3 + (size_t)e * HH * DD + n0);

    const int srow = lane >> 2;
    const int skb  = ((lane & 3) ^ ((lane >> 3) & 3)) * 16;
    const int brow_i = lane >> 4;

    f32x4 acc[8] = {};

    for (int k0 = 0; k0 < HH; k0 += 128) {
        // ---- A staging (DMA): 32 insts, wave w does idx 8w..8w+7 ----
        #pragma unroll
        for (int j = 0; j < 8; ++j) {
            const int idx = 8 * w + j;
            const int h = idx >> 3, c = idx & 7;     // h: 32-k half (0..3)
            const size_t rb = (size_t)(c * 16 + srow) * (HH * 2)
                            + (size_t)k0 * 2 + h * 64 + skb;
            __builtin_amdgcn_global_load_lds((const AS1 void*)(Ab + rb),
                (AS3 void*)((char*)As + idx * 1024), 16, 0, 0);
        }
        // ---- B staging (DMA): 8 insts per wave; rows w*32..w*32+31 ----
        #pragma unroll
        for (int i = 0; i < 8; ++i) {
            const int krow = w * 32 + i * 4 + brow_i;
            const int bscc = ((lane & 15) ^ ((5 * (4 * w + (i >> 1))) & 15)) * 16;
            const size_t sb = (size_t)(k0 + krow) * (DD * 4) + bscc;
            __builtin_amdgcn_global_load_lds((const AS1 void*)(W3b + sb),
                (AS3 void*)((char*)Bs + w * 8192 + i * 1024), 16, 0, 0);
        }
        __syncthreads();
        #pragma unroll
        for (int h = 0; h < 4; ++h) {
            bf16x8 av[8];
            #pragma unroll
            for (int m = 0; m < 8; ++m) {
                const int row = m * 16 + lr;
                const int sl  = (lq ^ ((row >> 1) & 3)) * 16;
                av[m] = *(const bf16x8*)((const char*)As + h * 8192 + row * 64 + sl);
            }
            const int n   = w * 16 + lr;
            const int lqh = h * 4 + lq;               // 0..15
            const int cb  = ((((n >> 2) ^ (5 * lqh)) & 15) << 4) + (n & 3) * 4;
            union { u32 q[4]; bf16x8 v; } u3;
            #pragma unroll
            for (int i = 0; i < 4; ++i) {
                int o = (lqh * 8 + 2 * i) * 256 + cb;
                asm("" : "+v"(o));
                u3.q[i] = pkbf(*(const float*)((const char*)Bs + o),
                               *(const float*)((const char*)Bs + o + 256));
            }
            const bf16x8 b3 = u3.v;
            #pragma unroll
            for (int m = 0; m < 8; ++m)
                acc[m] = __builtin_amdgcn_mfma_f32_16x16x32_bf16(av[m], b3, acc[m], 0, 0, 0);
        }
        __syncthreads();
    }

    u16* Oe = EO + (size_t)e * CAP * DD;
    const int cc = n0 + w * 16 + lr;
    #pragma unroll
    for (int m = 0; m < 8; ++m)
        #pragma unroll
        for (int r = 0; r < 4; ++r) {
            const int rr = m0 + m * 16 + lq * 4 + r;
            Oe[(size_t)rr * DD + cc] = f2bf(acc[m][r]);
        }
}

// ---------------------------------------------------------------------------
// 7. Combine: out[t] = g0*(kept0 ? EO[e0][p0] : x) + g1*(...)   (EO is bf16)
// ---------------------------------------------------------------------------
__global__ __launch_bounds__(256) void combine_kernel(
    const float* __restrict__ x, const u16* __restrict__ EO,
    const int4* __restrict__ meta, const float2* __restrict__ gates,
    float* __restrict__ out)
{
    int t = blockIdx.x;
    int d = threadIdx.x * 4;
    int4  m = meta[t];
    float2 g = gates[t];
    float4 xv = *(const float4*)(x + (size_t)t * DD + d);
    float4 v0 = xv, v1 = xv;
    if (m.y >= 0) {
        u16x4 q = *(const u16x4*)(EO + ((size_t)m.x * CAP + m.y) * DD + d);
        v0 = make_float4(bf2f(q[0]), bf2f(q[1]), bf2f(q[2]), bf2f(q[3]));
    }
    if (m.w >= 0) {
        u16x4 q = *(const u16x4*)(EO + ((size_t)m.z * CAP + m.w) * DD + d);
        v1 = make_float4(bf2f(q[0]), bf2f(q[1]), bf2f(q[2]), bf2f(q[3]));
    }
    float4 r;
    r.x = g.x * v0.x + g.y * v1.x;
    r.y = g.x * v0.y + g.y * v1.y;
    r.z = g.x * v0.z + g.y * v1.z;
    r.w = g.x * v0.w + g.y * v1.w;
    *(float4*)(out + (size_t)t * DD + d) = r;
}

// ---------------------------------------------------------------------------
extern "C" void kernel_launch(void* const* d_in, const int* in_sizes, int n_in,
                              void* d_out, int out_size, void* d_ws, size_t ws_size,
                              hipStream_t stream)
{
    const float* x  = (const float*)d_in[0];
    const float* rw = (const float*)d_in[1];
    const float* rb = (const float*)d_in[2];
    const float* w1 = (const float*)d_in[3];
    const float* w2 = (const float*)d_in[4];
    const float* w3 = (const float*)d_in[5];
    float* out = (float*)d_out;

    char* ws = (char*)d_ws;
    size_t off = 0;
    auto alloc = [&](size_t bytes) { char* p = ws + off; off = (off + bytes + 255) & ~(size_t)255; return p; };

    int2*   assign   = (int2*)  alloc(BT * sizeof(int2));
    float2* gates    = (float2*)alloc(BT * sizeof(float2));
    int4*   meta     = (int4*)  alloc(BT * sizeof(int4));
    int2*   slot_tok = (int2*)  alloc(EE * CAP * sizeof(int2));
    u16*    grouped  = (u16*)   alloc((size_t)EE * CAP * DD * 2);   //  8.4 MB
    u16*    Hbuf     = (u16*)   alloc((size_t)EE * CAP * HH * 2);   // 16.8 MB
    u16*    eo       = (u16*)   alloc((size_t)EE * CAP * DD * 2);   //  8.4 MB
    (void)ws_size;

    router_kernel<<<BT, 256, 0, stream>>>(x, rw, rb, assign, gates);
    scan_kernel<<<1, 64, 0, stream>>>(assign, meta, slot_tok);
    gather_bf16<<<EE * CAP, 256, 0, stream>>>(x, slot_tok, grouped);

    gemm1_mfma<<<dim3(HH / 64, CAP / 256, EE), 512, 0, stream>>>(grouped, w1, w2, Hbuf);
    gemm2_mfma<<<512, 256, 0, stream>>>(Hbuf, w3, eo);

    combine_kernel<<<BT, 256, 0, stream>>>(x, eo, meta, gates, out);
}